// Round 10
// baseline (242.231 us; speedup 1.0000x reference)
//
#include <hip/hip_runtime.h>
#include <cstdint>

#define NB 64
#define NC 256
#define ND 256
#define NT 4096

#define BT 32                    // t-columns per tile
#define NTILES 16                // tiles per block
#define CHUNK (BT * NTILES)      // 512 t per block
#define NCHUNK (NT / CHUNK)      // 8 chunks -> grid (8, 64) = 512 blocks = 2 per CU

typedef __attribute__((ext_vector_type(8)))  _Float16 half8;
typedef __attribute__((ext_vector_type(16))) float    f32x16;

union FragA { uint32_t u[4]; half8 v; };

__device__ __forceinline__ uint32_t pk_f16(float lo, float hi) {
    // v_cvt_pkrtz_f16_f32: D.lo=f16(lo), D.hi=f16(hi) — matches MFMA (k even, k odd) packing
    return __builtin_bit_cast(uint32_t, __builtin_amdgcn_cvt_pkrtz(lo, hi));
}

// BARRIER-FREE design. Evidence trail: R5 (intra-block scheduling: no effect),
// R7 (2 independent barrier groups/CU: -28%), R8/R9 (grid changes: worse).
// Diagnosis: the per-tile __syncthreads vmcnt(0) drain lock-stepping all waves
// is the exposed-latency term. Fix: eliminate sharing entirely.
//
// The MFMA B-fragment (n = lane&31 = t, k = 8*(lane>>5)+j = c) is DIRECTLY
// loadable from x[c][t] global memory, coalesced (each wave-load touches two
// c-rows x 128 B contiguous). So: no LDS, no staging, no __syncthreads —
// 16 independent wave-streams per CU. The 8x cross-wave x-reuse (one 32KB
// tile read by all 8 d-waves of a block) is served by L1/L2 (~2 GB over the
// kernel ~ 58 us at L2's 34.5 TB/s, overlapped), HBM still reads x once.
//
// Grid/dispatch: EXACT R7 2-D grid (8,64) — both remaps (R8, R9) regressed.
// W path, cvt packing, store layout: unchanged from the validated kernels.
//
// MFMA: D[m=d][n=t] = sum_c W^T[d][c] * X[c][t]
//   A = W frag (lane&31 = d), B = x frag (lane&31 = t), k = 8*(lane>>5)+j
//   C/D: col = lane&31 = t -> coalesced 4B/lane stores.
__global__ __launch_bounds__(512, 4)
void subject_gemm(const float* __restrict__ x,
                  const int*   __restrict__ subjects,
                  const float* __restrict__ w,
                  float*       __restrict__ out)
{
    const int tid  = threadIdx.x;
    const int lane = tid & 63;
    const int wv   = tid >> 6;      // 0..7 : d-subtile
    const int g    = lane >> 5;     // k-group / c-half
    const int l31  = lane & 31;     // t within tile (B), d within subtile (A)
    const int b    = blockIdx.y;
    const int t0   = blockIdx.x * CHUNK;

    const int sub = subjects[b];
    const float* __restrict__ wsub = w + (size_t)sub * NC * ND;
    const float* __restrict__ xb   = x + (size_t)b * NC * NT;
    float*       __restrict__ ob   = out + (size_t)b * ND * NT;

    const int dlane = wv * 32 + l31;

    // ---- one-time: W fragments (fp16) in registers; lane&31 = d, k(c) = 8g+j ----
    half8 wf[16];
#pragma unroll
    for (int ks = 0; ks < 16; ++ks) {
        float f[8];
#pragma unroll
        for (int j = 0; j < 8; ++j)
            f[j] = wsub[(size_t)(ks * 16 + g * 8 + j) * ND + dlane];
        FragA tmp;
#pragma unroll
        for (int p = 0; p < 4; ++p) tmp.u[p] = pk_f16(f[2 * p], f[2 * p + 1]);
        wf[ks] = tmp.v;
    }

    // per-lane x base: row (g*8) stride is folded into the loop's c index
    const float* xw = xb + (size_t)(g * 8) * NT + t0 + l31;

    for (int tile = 0; tile < NTILES; ++tile) {
        const float* xt = xw + tile * BT;

        // ---- compute: 32(d) x 32(t) per wave, K=256 in 16 MFMA steps ----
        // loads for step ks are independent of MFMA ks-1: the unrolled body
        // lets the compiler run fragment loads ahead under counted vmcnt.
        f32x16 acc = {};
#pragma unroll
        for (int ks = 0; ks < 16; ++ks) {
            float f[8];
#pragma unroll
            for (int j = 0; j < 8; ++j)
                f[j] = xt[(size_t)(ks * 16 + j) * NT];
            FragA bf;
#pragma unroll
            for (int p = 0; p < 4; ++p) bf.u[p] = pk_f16(f[2 * p], f[2 * p + 1]);
            acc = __builtin_amdgcn_mfma_f32_32x32x16_f16(wf[ks], bf.v, acc, 0, 0, 0);
        }

        // ---- store: col = lane&31 = t ; row d = (reg&3) + 8*(reg>>2) + 4*g ----
        const int tcol = t0 + tile * BT;
#pragma unroll
        for (int rg = 0; rg < 16; ++rg) {
            const int drow = wv * 32 + (rg & 3) + 8 * (rg >> 2) + 4 * g;
            ob[(size_t)drow * NT + tcol + l31] = acc[rg];
        }
    }
}

extern "C" void kernel_launch(void* const* d_in, const int* in_sizes, int n_in,
                              void* d_out, int out_size, void* d_ws, size_t ws_size,
                              hipStream_t stream)
{
    const float* x        = (const float*)d_in[0];
    const int*   subjects = (const int*)d_in[1];
    const float* w        = (const float*)d_in[2];
    float*       out      = (float*)d_out;

    dim3 grid(NCHUNK, NB);   // (8, 64) — R7's known-good dispatch layout
    subject_gemm<<<grid, 512, 0, stream>>>(x, subjects, w, out);
}

// Round 11
// 129.703 us; speedup vs baseline: 1.8676x; 1.8676x over previous
//
#include <hip/hip_runtime.h>
#include <cstdint>

#define NB 64
#define NC 256
#define ND 256
#define NT 4096

#define BT 32                    // t-columns per tile
#define NTILES 16                // tiles per block
#define CHUNK (BT * NTILES)      // 512 t per block
#define NCHUNK (NT / CHUNK)      // 8 chunks -> grid (8, 64) = 512 blocks = 2 per CU

typedef __attribute__((ext_vector_type(8)))  _Float16 half8;
typedef __attribute__((ext_vector_type(16))) float    f32x16;

union FragA { uint32_t u[4]; uint4 q; half8 v; };

__device__ __forceinline__ uint32_t pk_f16(float lo, float hi) {
    // v_cvt_pkrtz_f16_f32: D.lo=f16(lo), D.hi=f16(hi) — matches MFMA (k even, k odd) packing
    return __builtin_bit_cast(uint32_t, __builtin_amdgcn_cvt_pkrtz(lo, hi));
}

// EXACT R7 structure (126 µs known-good) with ONE change: output stores moved
// AFTER __syncthreads. R7's per-tile critical path ended with
//   stores-issue -> ~100cyc cvt/ds_write -> __syncthreads[vmcnt(0) drain]
// i.e. every tile the block waited ~full store-ack latency. Now tile T's
// stores issue after barrier T and drain at barrier T+1, with a whole tile
// of load+compute to complete under. Pure reorder: acc is registers across
// the barrier; every LDS hazard relation identical to R7.
//
// Evidence trail: R8 (4 blocks/CU): W re-fetch blowup, 3.5x worse. R9 (XCD
// remap): worse. R10 (no LDS, direct global frags): VMEM-issue-bound, 1.9x
// worse. R6 (custom lgkm-only barrier): raced under replay. Keep: 512-thread
// blocks, 2/CU, 32 KiB LDS, plain __syncthreads, grid (8,64).
//
// LDS (per buffer, 16 KiB): fp16 x-tile [t=0..31][c=0..255], row = 512 B,
// byte(t,c) = t*512 + ((2c) ^ ((t&15)<<4))  — XOR swizzle, same on write & read.
//
// MFMA: D[m=d][n=t] = sum_c W^T[d][c] * X[c][t]
//   A = W frag (lane&31 = d, k = 8*(lane>>5)+j), B = x frag (lane&31 = t)
//   C/D: col = lane&31 = t -> coalesced 4B/lane stores.
__global__ __launch_bounds__(512, 4)
void subject_gemm(const float* __restrict__ x,
                  const int*   __restrict__ subjects,
                  const float* __restrict__ w,
                  float*       __restrict__ out)
{
    __shared__ __align__(16) unsigned char lds[2 * 32 * 512];   // 32 KiB total

    const int tid  = threadIdx.x;
    const int lane = tid & 63;
    const int wv   = tid >> 6;      // 0..7 : d-subtile
    const int g    = lane >> 5;     // k-group / c-half
    const int l31  = lane & 31;     // t within tile (and d within subtile for W)
    const int b    = blockIdx.y;
    const int t0   = blockIdx.x * CHUNK;

    const int sub = subjects[b];
    const float* __restrict__ wsub = w + (size_t)sub * NC * ND;
    const float* __restrict__ xb   = x + (size_t)b * NC * NT;
    float*       __restrict__ ob   = out + (size_t)b * ND * NT;

    const int dlane = wv * 32 + l31;

    // ---- one-time: W fragments (fp16) in registers; lane&31 = d, k(c) = 8g+j ----
    half8 wf[16];
#pragma unroll
    for (int ks = 0; ks < 16; ++ks) {
        float f[8];
#pragma unroll
        for (int j = 0; j < 8; ++j)
            f[j] = wsub[(size_t)(ks * 16 + g * 8 + j) * ND + dlane];
        FragA tmp;
#pragma unroll
        for (int p = 0; p < 4; ++p) tmp.u[p] = pk_f16(f[2 * p], f[2 * p + 1]);
        wf[ks] = tmp.v;
    }

    // ---- staging: thread owns c in [c0, c0+16), t = l31 ----
    const int c0 = wv * 32 + g * 16;
    const uint32_t swz      = ((uint32_t)(l31 & 15)) << 4;
    const uint32_t wr_byte0 = (uint32_t)l31 * 512 + (((uint32_t)c0 * 2 +  0) ^ swz);
    const uint32_t wr_byte1 = (uint32_t)l31 * 512 + (((uint32_t)c0 * 2 + 16) ^ swz);
    const uint32_t rd_row   = (uint32_t)l31 * 512;

    const float* xg = xb + (size_t)c0 * NT + t0 + l31;   // + i*NT + tile*BT

    float stage[16];

    // prologue: stage tile 0
#pragma unroll
    for (int i = 0; i < 16; ++i) stage[i] = xg[(size_t)i * NT];
    {
        uint4 q0, q1;
        q0.x = pk_f16(stage[0],  stage[1]);  q0.y = pk_f16(stage[2],  stage[3]);
        q0.z = pk_f16(stage[4],  stage[5]);  q0.w = pk_f16(stage[6],  stage[7]);
        q1.x = pk_f16(stage[8],  stage[9]);  q1.y = pk_f16(stage[10], stage[11]);
        q1.z = pk_f16(stage[12], stage[13]); q1.w = pk_f16(stage[14], stage[15]);
        *reinterpret_cast<uint4*>(&lds[wr_byte0]) = q0;
        *reinterpret_cast<uint4*>(&lds[wr_byte1]) = q1;
    }
    __syncthreads();

    for (int tile = 0; tile < NTILES; ++tile) {
        const uint32_t bufoff = (uint32_t)(tile & 1) * 16384;

        // issue next tile's 16 global loads first; pin them above compute
        if (tile + 1 < NTILES) {
            const float* src = xg + (size_t)(tile + 1) * BT;
#pragma unroll
            for (int i = 0; i < 16; ++i) stage[i] = src[(size_t)i * NT];
            __builtin_amdgcn_sched_barrier(0);
        }

        // ---- compute: 32(d) x 32(t) per wave, K=256 in 16 MFMA steps ----
        f32x16 acc = {};
#pragma unroll
        for (int ks = 0; ks < 16; ++ks) {
            const uint32_t colb = ((uint32_t)(ks * 32 + g * 16)) ^ swz;
            FragA a;
            a.q = *reinterpret_cast<const uint4*>(&lds[bufoff + rd_row + colb]);
            acc = __builtin_amdgcn_mfma_f32_32x32x16_f16(wf[ks], a.v, acc, 0, 0, 0);
        }

        // convert + ds_write staged tile into the other buffer
        if (tile + 1 < NTILES) {
            const uint32_t nb = (uint32_t)((tile + 1) & 1) * 16384;
            uint4 q0, q1;
            q0.x = pk_f16(stage[0],  stage[1]);  q0.y = pk_f16(stage[2],  stage[3]);
            q0.z = pk_f16(stage[4],  stage[5]);  q0.w = pk_f16(stage[6],  stage[7]);
            q1.x = pk_f16(stage[8],  stage[9]);  q1.y = pk_f16(stage[10], stage[11]);
            q1.z = pk_f16(stage[12], stage[13]); q1.w = pk_f16(stage[14], stage[15]);
            *reinterpret_cast<uint4*>(&lds[nb + wr_byte0]) = q0;
            *reinterpret_cast<uint4*>(&lds[nb + wr_byte1]) = q1;
        }
        __syncthreads();

        // ---- store AFTER the barrier: these acks drain at the NEXT barrier,
        // with a full tile of load+compute time to complete under. ----
        // col = lane&31 = t ; row d = (reg&3) + 8*(reg>>2) + 4*g
        const int tcol = t0 + tile * BT;
#pragma unroll
        for (int rg = 0; rg < 16; ++rg) {
            const int drow = wv * 32 + (rg & 3) + 8 * (rg >> 2) + 4 * g;
            ob[(size_t)drow * NT + tcol + l31] = acc[rg];
        }
    }
}

extern "C" void kernel_launch(void* const* d_in, const int* in_sizes, int n_in,
                              void* d_out, int out_size, void* d_ws, size_t ws_size,
                              hipStream_t stream)
{
    const float* x        = (const float*)d_in[0];
    const int*   subjects = (const int*)d_in[1];
    const float* w        = (const float*)d_in[2];
    float*       out      = (float*)d_out;

    dim3 grid(NCHUNK, NB);   // (8, 64) — R7's known-good dispatch layout
    subject_gemm<<<grid, 512, 0, stream>>>(x, subjects, w, out);
}